// Round 1
// baseline (29010.544 us; speedup 1.0000x reference)
//
#include <hip/hip_runtime.h>
#include <hip/hip_fp16.h>

#define T_LEN 8192
#define E_DIM 512
#define H_DIM 512
#define G4    2048   // 4*H
#define KTAGS 19
#define START_TAG 17
#define STOP_TAG  18
#define NEGV  (-10000.0f)
#define NWG   16     // workgroups per direction

__device__ __forceinline__ float sigmoidf_(float x) { return 1.0f / (1.0f + expf(-x)); }

// ---------------- K1: xg[dir][t][n] = dot(x[t or T-1-t], w_ih[n]) + b_ih[n] + b_hh[n]
template<bool XG16>
__global__ __launch_bounds__(256) void k_xg(
    const float* __restrict__ x,
    const float* __restrict__ wih_f, const float* __restrict__ bih_f, const float* __restrict__ bhh_f,
    const float* __restrict__ wih_b, const float* __restrict__ bih_b, const float* __restrict__ bhh_b,
    void* __restrict__ xg_out)
{
  const int dir = blockIdx.z;
  const float* __restrict__ wih = dir ? wih_b : wih_f;
  const float* __restrict__ bih = dir ? bih_b : bih_f;
  const float* __restrict__ bhh = dir ? bhh_b : bhh_f;
  __shared__ float xs[16][68];   // [k][m] transposed-on-write, padded
  __shared__ float wsd[16][68];  // [k][n]
  const int tid = threadIdx.x;
  const int tm = tid >> 4, tn = tid & 15;
  const int m0 = blockIdx.y * 64, n0 = blockIdx.x * 64;
  const int lr = tid >> 2;          // 0..63: tile row
  const int lk = (tid & 3) << 2;    // 0,4,8,12
  float acc[4][4] = {{0.f,0.f,0.f,0.f},{0.f,0.f,0.f,0.f},{0.f,0.f,0.f,0.f},{0.f,0.f,0.f,0.f}};
  for (int k0 = 0; k0 < E_DIM; k0 += 16) {
    const int gm = m0 + lr;
    const int xrow = dir ? (T_LEN - 1 - gm) : gm;
    const float4 xa = *reinterpret_cast<const float4*>(&x[(size_t)xrow * E_DIM + k0 + lk]);
    const float4 wa = *reinterpret_cast<const float4*>(&wih[(size_t)(n0 + lr) * E_DIM + k0 + lk]);
    __syncthreads();
    xs[lk+0][lr] = xa.x; xs[lk+1][lr] = xa.y; xs[lk+2][lr] = xa.z; xs[lk+3][lr] = xa.w;
    wsd[lk+0][lr] = wa.x; wsd[lk+1][lr] = wa.y; wsd[lk+2][lr] = wa.z; wsd[lk+3][lr] = wa.w;
    __syncthreads();
    #pragma unroll
    for (int kk = 0; kk < 16; ++kk) {
      const float4 a = *reinterpret_cast<const float4*>(&xs[kk][tm << 2]);
      const float4 b = *reinterpret_cast<const float4*>(&wsd[kk][tn << 2]);
      acc[0][0] += a.x*b.x; acc[0][1] += a.x*b.y; acc[0][2] += a.x*b.z; acc[0][3] += a.x*b.w;
      acc[1][0] += a.y*b.x; acc[1][1] += a.y*b.y; acc[1][2] += a.y*b.z; acc[1][3] += a.y*b.w;
      acc[2][0] += a.z*b.x; acc[2][1] += a.z*b.y; acc[2][2] += a.z*b.z; acc[2][3] += a.z*b.w;
      acc[3][0] += a.w*b.x; acc[3][1] += a.w*b.y; acc[3][2] += a.w*b.z; acc[3][3] += a.w*b.w;
    }
  }
  const int n = n0 + (tn << 2);
  float4 bb;
  bb.x = bih[n+0] + bhh[n+0];
  bb.y = bih[n+1] + bhh[n+1];
  bb.z = bih[n+2] + bhh[n+2];
  bb.w = bih[n+3] + bhh[n+3];
  if (XG16) {
    __half* o = reinterpret_cast<__half*>(xg_out) + (size_t)dir * T_LEN * G4;
    #pragma unroll
    for (int mi = 0; mi < 4; ++mi) {
      const size_t base = (size_t)(m0 + (tm << 2) + mi) * G4 + n;
      o[base+0] = __float2half(acc[mi][0] + bb.x);
      o[base+1] = __float2half(acc[mi][1] + bb.y);
      o[base+2] = __float2half(acc[mi][2] + bb.z);
      o[base+3] = __float2half(acc[mi][3] + bb.w);
    }
  } else {
    float* o = reinterpret_cast<float*>(xg_out) + (size_t)dir * T_LEN * G4;
    #pragma unroll
    for (int mi = 0; mi < 4; ++mi) {
      const size_t base = (size_t)(m0 + (tm << 2) + mi) * G4 + n;
      float4 st; st.x = acc[mi][0] + bb.x; st.y = acc[mi][1] + bb.y;
      st.z = acc[mi][2] + bb.z; st.w = acc[mi][3] + bb.w;
      *reinterpret_cast<float4*>(&o[base]) = st;
    }
  }
}

// ---------------- K2: persistent bidirectional LSTM recurrence.
// 32 blocks x 512 threads. Blocks (b%8)<4 -> forward dir, else backward.
// Each block owns 32 h-indices (=128 gate rows); w_hh rows live in VGPRs.
template<bool XG16>
__global__ __launch_bounds__(512, 2) void k_lstm(
    const float* __restrict__ whh_f, const float* __restrict__ whh_b,
    const float* __restrict__ h0, const float* __restrict__ c0,
    const void* __restrict__ xg_base, float* __restrict__ h_hist,
    unsigned int* __restrict__ cnt)
{
  const int b = blockIdx.x;
  const int dir = ((b & 7) < 4) ? 0 : 1;                 // XCD-grouping heuristic
  const int idx = (b & 3) + ((b >> 3) << 2);             // 0..15 slice within dir
  const float* __restrict__ whh = dir ? whh_b : whh_f;
  const float* xg32 = reinterpret_cast<const float*>(xg_base) + (size_t)dir * T_LEN * G4;
  const __half* xg16 = reinterpret_cast<const __half*>(xg_base) + (size_t)dir * T_LEN * G4;
  float* hh = h_hist + (size_t)dir * T_LEN * H_DIM;
  unsigned int* cn = cnt + (size_t)dir * T_LEN;

  const int tid = threadIdx.x;
  const int w = tid >> 6, l = tid & 63;
  const int r = (w << 4) + (l & 15);   // 0..127: local gate row
  const int c = l >> 4;                // 0..3: 128-wide k-chunk
  const int gate = r >> 5, j = r & 31;
  const int H0 = idx * 32;
  const int row = gate * H_DIM + H0 + j;   // global gate row (i,f,g,o order)

  // Hold this thread's 128 weights in VGPRs (static indices only).
  float4 wreg[32];
  {
    const float4* wr4 = reinterpret_cast<const float4*>(&whh[(size_t)row * H_DIM + c * 128]);
    #pragma unroll
    for (int kk = 0; kk < 32; ++kk) wreg[kk] = wr4[kk];
  }

  __shared__ float h_lds[4 * 132];   // per-chunk stride 132 -> 4 distinct banks
  __shared__ float gates[128];
  float cstate = (tid < 32) ? c0[dir * H_DIM + H0 + tid] : 0.f;

  for (int t = 0; t < T_LEN; ++t) {
    const float xgv = XG16 ? __half2float(xg16[(size_t)t * G4 + row])
                           : xg32[(size_t)t * G4 + row];
    if (t > 0) {
      if (tid == 0) {
        while (__hip_atomic_load(&cn[t - 1], __ATOMIC_ACQUIRE, __HIP_MEMORY_SCOPE_AGENT) < NWG)
          __builtin_amdgcn_s_sleep(1);
      }
      __syncthreads();
      const float hv = __hip_atomic_load(&hh[(size_t)(t - 1) * H_DIM + tid],
                                         __ATOMIC_RELAXED, __HIP_MEMORY_SCOPE_AGENT);
      h_lds[((tid >> 7) * 132) + (tid & 127)] = hv;
    } else {
      h_lds[((tid >> 7) * 132) + (tid & 127)] = h0[dir * H_DIM + tid];
    }
    __syncthreads();

    float acc = 0.f;
    const float* hc = &h_lds[c * 132];
    #pragma unroll
    for (int kk = 0; kk < 32; ++kk) {
      const float4 hv4 = *reinterpret_cast<const float4*>(&hc[kk << 2]);
      const float4 wv = wreg[kk];
      acc += wv.x * hv4.x + wv.y * hv4.y + wv.z * hv4.z + wv.w * hv4.w;
    }
    acc += __shfl_xor(acc, 16, 64);
    acc += __shfl_xor(acc, 32, 64);
    if (c == 0) gates[r] = acc + xgv;
    __syncthreads();

    if (tid < 32) {
      const float gi = gates[tid];
      const float gf = gates[32 + tid];
      const float gg = gates[64 + tid];
      const float go = gates[96 + tid];
      cstate = sigmoidf_(gf) * cstate + sigmoidf_(gi) * tanhf(gg);
      const float hval = sigmoidf_(go) * tanhf(cstate);
      __hip_atomic_store(&hh[(size_t)t * H_DIM + H0 + tid], hval,
                         __ATOMIC_RELAXED, __HIP_MEMORY_SCOPE_AGENT);
    }
    __syncthreads();   // drains vmcnt: slice stores device-visible before the release-add
    if (tid == 0)
      __hip_atomic_fetch_add(&cn[t], 1u, __ATOMIC_RELEASE, __HIP_MEMORY_SCOPE_AGENT);
  }
}

// ---------------- K3: feats[t][k] = b_tag[k] + [h_f(t), h_b(T-1-t)] . W_tag[k]
__global__ __launch_bounds__(64) void k_feats(
    const float* __restrict__ h_hist, const float* __restrict__ Wtag,
    const float* __restrict__ btag, float* __restrict__ feats)
{
  const int t = blockIdx.x;
  const int k = threadIdx.x;
  if (k >= KTAGS) return;
  const float* hf  = &h_hist[(size_t)t * H_DIM];
  const float* hbp = &h_hist[(size_t)T_LEN * H_DIM + (size_t)(T_LEN - 1 - t) * H_DIM];
  const float* wr  = &Wtag[(size_t)k * (2 * H_DIM)];
  float acc = btag[k];
  #pragma unroll 8
  for (int d = 0; d < H_DIM / 4; ++d) {
    const float4 h4 = *reinterpret_cast<const float4*>(&hf[d << 2]);
    const float4 w4 = *reinterpret_cast<const float4*>(&wr[d << 2]);
    acc += h4.x*w4.x + h4.y*w4.y + h4.z*w4.z + h4.w*w4.w;
  }
  #pragma unroll 8
  for (int d = 0; d < H_DIM / 4; ++d) {
    const float4 h4 = *reinterpret_cast<const float4*>(&hbp[d << 2]);
    const float4 w4 = *reinterpret_cast<const float4*>(&wr[H_DIM + (d << 2)]);
    acc += h4.x*w4.x + h4.y*w4.y + h4.z*w4.z + h4.w*w4.w;
  }
  feats[(size_t)t * KTAGS + k] = acc;
}

// ---------------- K4: Viterbi forward scan (1 wave; fv in regs, shfl broadcast)
__global__ __launch_bounds__(64) void k_viterbi(
    const float* __restrict__ feats, const float* __restrict__ trans,
    float* __restrict__ d_out, unsigned char* __restrict__ bptr, int* __restrict__ best)
{
  const int l = threadIdx.x;
  const bool act = (l < KTAGS);
  float trow[KTAGS];
  #pragma unroll
  for (int jj = 0; jj < KTAGS; ++jj)
    trow[jj] = act ? trans[l * KTAGS + jj] : NEGV;
  const float trs = act ? trans[STOP_TAG * KTAGS + l] : NEGV;
  float fv = act ? ((l == START_TAG) ? 0.f : NEGV) : -3.4e38f;
  float fbuf[4];
  #pragma unroll
  for (int q = 0; q < 4; ++q) fbuf[q] = act ? feats[(size_t)q * KTAGS + l] : 0.f;

  for (int t = 0; t < T_LEN; t += 4) {
    #pragma unroll
    for (int u = 0; u < 4; ++u) {
      const int tt = t + u;
      const float fcur = fbuf[u];
      if (act && (tt + 4 < T_LEN)) fbuf[u] = feats[(size_t)(tt + 4) * KTAGS + l];
      float m = -3.4e38f; int am = 0;
      #pragma unroll
      for (int jj = 0; jj < KTAGS; ++jj) {
        const float fvj = __shfl(fv, jj, 64);
        const float v = fvj + trow[jj];
        if (v > m) { m = v; am = jj; }      // ascending j + strict > = first-max
      }
      fv = m + fcur;
      if (act) bptr[(size_t)tt * KTAGS + l] = (unsigned char)am;
    }
  }
  float tv = act ? (fv + trs) : -3.4e38f;
  int bi = l;
  #pragma unroll
  for (int off = 1; off < 64; off <<= 1) {
    const float ov = __shfl_xor(tv, off, 64);
    const int oi = __shfl_xor(bi, off, 64);
    if (ov > tv || (ov == tv && oi < bi)) { tv = ov; bi = oi; }
  }
  if (l == 0) { d_out[0] = tv; *best = bi; }
}

// ---------------- K5: per-chunk backpointer-function composition (parallel)
__global__ __launch_bounds__(64) void k_chunkF(
    const unsigned char* __restrict__ bptr, unsigned char* __restrict__ F)
{
  const int cidx = blockIdx.x;
  const int g = threadIdx.x;
  if (g >= KTAGS) return;
  const int e = (cidx + 1) * 128 - 1, s = cidx * 128;
  int tag = g;
  for (int t = e; t >= s; --t) tag = bptr[(size_t)t * KTAGS + tag];
  F[cidx * KTAGS + g] = (unsigned char)tag;
}

// ---------------- K6: sequential combine of 64 chunk functions
__global__ void k_bounds(const unsigned char* __restrict__ F,
                         const int* __restrict__ best, int* __restrict__ boundary)
{
  if (threadIdx.x != 0 || blockIdx.x != 0) return;
  int tag = *best;
  boundary[63] = tag;
  for (int cidx = 63; cidx >= 1; --cidx) {
    tag = F[cidx * KTAGS + tag];
    boundary[cidx - 1] = tag;
  }
}

// ---------------- K7: per-chunk path fill (parallel)
__global__ __launch_bounds__(64) void k_path(
    const unsigned char* __restrict__ bptr, const int* __restrict__ boundary,
    float* __restrict__ d_out)
{
  const int cidx = blockIdx.x;
  if (threadIdx.x != 0) return;
  const int e = (cidx + 1) * 128 - 1, s = cidx * 128;
  int tag = boundary[cidx];
  d_out[1 + e] = (float)tag;
  for (int t = e - 1; t >= s; --t) {
    tag = bptr[(size_t)(t + 1) * KTAGS + tag];
    d_out[1 + t] = (float)tag;
  }
}

extern "C" void kernel_launch(void* const* d_in, const int* in_sizes, int n_in,
                              void* d_out, int out_size, void* d_ws, size_t ws_size,
                              hipStream_t stream) {
  (void)in_sizes; (void)n_in; (void)out_size;
  const float* x      = (const float*)d_in[0];
  const float* wih_f  = (const float*)d_in[1];
  const float* whh_f  = (const float*)d_in[2];
  const float* bih_f  = (const float*)d_in[3];
  const float* bhh_f  = (const float*)d_in[4];
  const float* wih_b  = (const float*)d_in[5];
  const float* whh_b  = (const float*)d_in[6];
  const float* bih_b  = (const float*)d_in[7];
  const float* bhh_b  = (const float*)d_in[8];
  const float* h0     = (const float*)d_in[9];
  const float* c0     = (const float*)d_in[10];
  const float* Wtag   = (const float*)d_in[11];
  const float* btag   = (const float*)d_in[12];
  const float* trans  = (const float*)d_in[13];
  float* out = (float*)d_out;
  char* ws = (char*)d_ws;

  // workspace layout
  const bool xg16 = ws_size < ((size_t)168 << 20);   // need ~162MB for fp32 xg path
  size_t off = 0;
  auto alloc = [&](size_t bytes) -> void* {
    void* p = ws + off;
    off += (bytes + 255) & ~(size_t)255;
    return p;
  };
  const size_t xgN = (size_t)2 * T_LEN * G4;
  void* xg            = alloc(xgN * (xg16 ? 2 : 4));
  float* h_hist       = (float*)alloc((size_t)2 * T_LEN * H_DIM * 4);
  float* feats        = (float*)alloc((size_t)T_LEN * KTAGS * 4);
  unsigned char* bptr = (unsigned char*)alloc((size_t)T_LEN * KTAGS);
  unsigned int* cnt   = (unsigned int*)alloc((size_t)2 * T_LEN * 4);
  unsigned char* F    = (unsigned char*)alloc(64 * KTAGS);
  int* boundary       = (int*)alloc(64 * 4);
  int* best           = (int*)alloc(4);

  hipMemsetAsync(cnt, 0, (size_t)2 * T_LEN * 4, stream);

  const dim3 gx(G4 / 64, T_LEN / 64, 2);
  if (xg16) {
    k_xg<true><<<gx, 256, 0, stream>>>(x, wih_f, bih_f, bhh_f, wih_b, bih_b, bhh_b, xg);
    k_lstm<true><<<32, 512, 0, stream>>>(whh_f, whh_b, h0, c0, xg, h_hist, cnt);
  } else {
    k_xg<false><<<gx, 256, 0, stream>>>(x, wih_f, bih_f, bhh_f, wih_b, bih_b, bhh_b, xg);
    k_lstm<false><<<32, 512, 0, stream>>>(whh_f, whh_b, h0, c0, xg, h_hist, cnt);
  }
  k_feats<<<T_LEN, 64, 0, stream>>>(h_hist, Wtag, btag, feats);
  k_viterbi<<<1, 64, 0, stream>>>(feats, trans, out, bptr, best);
  k_chunkF<<<64, 64, 0, stream>>>(bptr, F);
  k_bounds<<<1, 64, 0, stream>>>(F, best, boundary);
  k_path<<<64, 64, 0, stream>>>(bptr, boundary, out);
}